// Round 6
// baseline (316.726 us; speedup 1.0000x reference)
//
#include <hip/hip_runtime.h>
#include <hip/hip_bf16.h>
#include <hip/hip_cooperative_groups.h>

namespace cg = cooperative_groups;

#define D_FEAT 128
#define NP 64                // nodes per partition
#define NP_SHIFT 6
#define P_PARTS 782          // ceil(50000/64)
#define CAP 1024             // edges per partition: mean 768, sd ~28 -> +9 sigma
#define EPB 2048             // edges per bucket block
#define XW_BLOCKS 196        // ceil(50000/256)
#define BK_BLOCKS 293        // ceil(600000/2048)
#define GRID 512             // coop grid: 2 blocks/CU worst case, co-residency safe

// ---------------------------------------------------------------------------
// logits = A^2 (x @ W_all) + A(1 g^T) + 1 c^T ;  out = softmax(logits)
//   W_all = diag(w1) Wd1 diag(w2) Wd2 Wout  (128x4)
//   g = b1^T diag(w2) Wd2 Wout,  c = b2^T Wout + bout
// Primary: ONE cooperative dispatch, 512 blocks, __launch_bounds__(256,4)
// (VGPR<=128 -> >=4 blocks/CU capacity; r5's 782-block version was silently
// rejected: needed 4 blocks/CU co-resident but VGPRs allowed only 3).
// Fallback on any launch error: r4's proven 3-dispatch path (same device fns).
// ---------------------------------------------------------------------------

__device__ __forceinline__ void phase_xw(
    int b, int t, int* sm, const float4* __restrict__ x4,
    const float* __restrict__ w1, const float* __restrict__ Wd1,
    const float* __restrict__ b1, const float* __restrict__ w2,
    const float* __restrict__ Wd2, const float* __restrict__ b2,
    const float* __restrict__ Wout, const float* __restrict__ bout,
    float* __restrict__ gc, float4* __restrict__ u4, int nN)
{
    float* T2   = (float*)sm;                // 64x4
    float* Wall = (float*)sm + 256;          // 128x4
    {
        int m = t >> 2, j = t & 3;
        float s = 0.f;
        for (int p = 0; p < 32; ++p) s += Wd2[m * 32 + p] * Wout[p * 4 + j];
        T2[t] = w2[m] * s;
    }
    __syncthreads();
    for (int idx = t; idx < 512; idx += 256) {
        int k = idx >> 2, j = idx & 3;
        float s = 0.f;
        for (int m = 0; m < 64; ++m) s += Wd1[k * 64 + m] * T2[m * 4 + j];
        Wall[idx] = w1[k] * s;
    }
    if (b == 0 && t < 4) {                   // publish g, c
        float s = 0.f;
        for (int m = 0; m < 64; ++m) s += b1[m] * T2[m * 4 + t];
        gc[t] = s;
        float s2 = 0.f;
        for (int p = 0; p < 32; ++p) s2 += b2[p] * Wout[p * 4 + t];
        gc[4 + t] = s2 + bout[t];
    }
    __syncthreads();
    int r = b * 256 + t;
    if (r < nN) {
        const float4* W = (const float4*)Wall;
        float4 acc = make_float4(0.f, 0.f, 0.f, 0.f);
        #pragma unroll 8
        for (int k4 = 0; k4 < 32; ++k4) {
            float4 xv = x4[(size_t)r * 32 + k4];
            float4 a0 = W[4 * k4 + 0];
            float4 a1 = W[4 * k4 + 1];
            float4 a2 = W[4 * k4 + 2];
            float4 a3 = W[4 * k4 + 3];
            acc.x += xv.x * a0.x + xv.y * a1.x + xv.z * a2.x + xv.w * a3.x;
            acc.y += xv.x * a0.y + xv.y * a1.y + xv.z * a2.y + xv.w * a3.y;
            acc.z += xv.x * a0.z + xv.y * a1.z + xv.z * a2.z + xv.w * a3.z;
            acc.w += xv.x * a0.w + xv.y * a1.w + xv.z * a2.w + xv.w * a3.w;
        }
        u4[r] = acc;
    }
}

__device__ __forceinline__ void phase_bucket(
    int bb, int t, int* sm,
    const int* __restrict__ src, const int* __restrict__ dst,
    int* __restrict__ partFill, int* __restrict__ edgeBuf, int nE)
{
    int* hist = sm;
    int* base = sm + P_PARTS;
    for (int p = t; p < P_PARTS; p += 256) hist[p] = 0;
    __syncthreads();
    const int4* dst4 = (const int4*)dst;
    const int4* src4 = (const int4*)src;
    int nE4  = nE >> 2;
    int b4   = bb * (EPB / 4);
    int end4 = min(b4 + EPB / 4, nE4);
    int ia = b4 + t, ib = b4 + 256 + t;
    bool va = ia < end4, vb = ib < end4;
    int4 da, sa, db, sb;                     // cached in regs across passes
    if (va) { da = dst4[ia]; sa = src4[ia]; }
    if (vb) { db = dst4[ib]; sb = src4[ib]; }
    if (va) {
        atomicAdd(&hist[da.x >> NP_SHIFT], 1);
        atomicAdd(&hist[da.y >> NP_SHIFT], 1);
        atomicAdd(&hist[da.z >> NP_SHIFT], 1);
        atomicAdd(&hist[da.w >> NP_SHIFT], 1);
    }
    if (vb) {
        atomicAdd(&hist[db.x >> NP_SHIFT], 1);
        atomicAdd(&hist[db.y >> NP_SHIFT], 1);
        atomicAdd(&hist[db.z >> NP_SHIFT], 1);
        atomicAdd(&hist[db.w >> NP_SHIFT], 1);
    }
    __syncthreads();
    for (int p = t; p < P_PARTS; p += 256) {
        int h = hist[p];
        base[p] = h ? atomicAdd(&partFill[p], h) : 0;
    }
    __syncthreads();
    auto place = [&](int d, int s) {
        int p = d >> NP_SHIFT;
        int rank = atomicSub(&hist[p], 1) - 1;
        int pos = base[p] + rank;
        if (pos < CAP)
            edgeBuf[p * CAP + pos] = s | ((d & (NP - 1)) << 16);
    };
    if (va) { place(da.x, sa.x); place(da.y, sa.y); place(da.z, sa.z); place(da.w, sa.w); }
    if (vb) { place(db.x, sb.x); place(db.y, sb.y); place(db.z, sb.z); place(db.w, sb.w); }
}

__device__ __forceinline__ void spmm_part(
    int p, int t, float* acc,
    const int* __restrict__ partFill, const int* __restrict__ edgeBuf,
    const float4* __restrict__ in4, const float* __restrict__ gc, int gcOff,
    float4* __restrict__ out4, int nN, bool doSoftmax)
{
    acc[t] = 0.f;
    __syncthreads();
    int n = min(partFill[p], CAP);
    const int4* eb4 = (const int4*)(edgeBuf + p * CAP);
    int i0 = t * 4;
    if (i0 < n) {
        int4 e4 = eb4[t];
        int ne = n - i0;                     // >= 1
        float4 v0 = in4[e4.x & 0xFFFF];
        float4 v1 = (ne > 1) ? in4[e4.y & 0xFFFF] : make_float4(0, 0, 0, 0);
        float4 v2 = (ne > 2) ? in4[e4.z & 0xFFFF] : make_float4(0, 0, 0, 0);
        float4 v3 = (ne > 3) ? in4[e4.w & 0xFFFF] : make_float4(0, 0, 0, 0);
        int d0 = e4.x >> 16, d1 = e4.y >> 16, d2 = e4.z >> 16, d3 = e4.w >> 16;
        atomicAdd(&acc[0 * NP + d0], v0.x);
        atomicAdd(&acc[1 * NP + d0], v0.y);
        atomicAdd(&acc[2 * NP + d0], v0.z);
        atomicAdd(&acc[3 * NP + d0], v0.w);
        if (ne > 1) {
            atomicAdd(&acc[0 * NP + d1], v1.x);
            atomicAdd(&acc[1 * NP + d1], v1.y);
            atomicAdd(&acc[2 * NP + d1], v1.z);
            atomicAdd(&acc[3 * NP + d1], v1.w);
        }
        if (ne > 2) {
            atomicAdd(&acc[0 * NP + d2], v2.x);
            atomicAdd(&acc[1 * NP + d2], v2.y);
            atomicAdd(&acc[2 * NP + d2], v2.z);
            atomicAdd(&acc[3 * NP + d2], v2.w);
        }
        if (ne > 3) {
            atomicAdd(&acc[0 * NP + d3], v3.x);
            atomicAdd(&acc[1 * NP + d3], v3.y);
            atomicAdd(&acc[2 * NP + d3], v3.z);
            atomicAdd(&acc[3 * NP + d3], v3.w);
        }
    }
    __syncthreads();
    if (t < NP) {
        int node = p * NP + t;
        if (node < nN) {
            float lx = acc[0 * NP + t] + gc[gcOff + 0];
            float ly = acc[1 * NP + t] + gc[gcOff + 1];
            float lz = acc[2 * NP + t] + gc[gcOff + 2];
            float lw = acc[3 * NP + t] + gc[gcOff + 3];
            if (doSoftmax) {
                float m = fmaxf(fmaxf(lx, ly), fmaxf(lz, lw));
                float ex = __expf(lx - m);
                float ey = __expf(ly - m);
                float ez = __expf(lz - m);
                float ew = __expf(lw - m);
                float r = 1.f / (ex + ey + ez + ew);
                out4[node] = make_float4(ex * r, ey * r, ez * r, ew * r);
            } else {
                out4[node] = make_float4(lx, ly, lz, lw);
            }
        }
    }
    __syncthreads();   // acc reused next grid-stride iteration
}

// ---- primary: single cooperative dispatch ----
__global__ __launch_bounds__(256, 4) void mega_kernel(
    const float4* __restrict__ x4,
    const int* __restrict__ src, const int* __restrict__ dst,
    const float* __restrict__ w1, const float* __restrict__ Wd1,
    const float* __restrict__ b1, const float* __restrict__ w2,
    const float* __restrict__ Wd2, const float* __restrict__ b2,
    const float* __restrict__ Wout, const float* __restrict__ bout,
    int* __restrict__ partFill, int* __restrict__ edgeBuf,
    float* __restrict__ gc, float4* __restrict__ u4, float4* __restrict__ v4,
    float4* __restrict__ out4, int nN, int nE)
{
    __shared__ int sm[2 * P_PARTS];
    cg::grid_group grid = cg::this_grid();
    int t = threadIdx.x, b = blockIdx.x;

    for (int zi = b * 256 + t; zi < P_PARTS; zi += GRID * 256) partFill[zi] = 0;
    grid.sync();

    if (b < XW_BLOCKS)
        phase_xw(b, t, sm, x4, w1, Wd1, b1, w2, Wd2, b2, Wout, bout, gc, u4, nN);
    else if (b < XW_BLOCKS + BK_BLOCKS)
        phase_bucket(b - XW_BLOCKS, t, sm, src, dst, partFill, edgeBuf, nE);
    grid.sync();

    for (int p = b; p < P_PARTS; p += GRID)
        spmm_part(p, t, (float*)sm, partFill, edgeBuf, u4, gc, 0, v4, nN, false);
    grid.sync();

    for (int p = b; p < P_PARTS; p += GRID)
        spmm_part(p, t, (float*)sm, partFill, edgeBuf, v4, gc, 4, out4, nN, true);
}

// ---- fallback: r4's proven 3-dispatch path ----
__global__ __launch_bounds__(256) void xw_bucket_kernel(
    const float4* __restrict__ x4,
    const int* __restrict__ src, const int* __restrict__ dst,
    const float* __restrict__ w1, const float* __restrict__ Wd1,
    const float* __restrict__ b1, const float* __restrict__ w2,
    const float* __restrict__ Wd2, const float* __restrict__ b2,
    const float* __restrict__ Wout, const float* __restrict__ bout,
    int* __restrict__ partFill, int* __restrict__ edgeBuf,
    float* __restrict__ gc, float4* __restrict__ u4, int nN, int nE)
{
    __shared__ int sm[2 * P_PARTS];
    int t = threadIdx.x, b = blockIdx.x;
    if (b < XW_BLOCKS)
        phase_xw(b, t, sm, x4, w1, Wd1, b1, w2, Wd2, b2, Wout, bout, gc, u4, nN);
    else
        phase_bucket(b - XW_BLOCKS, t, sm, src, dst, partFill, edgeBuf, nE);
}

__global__ __launch_bounds__(256) void spmm_kernel_sa(
    const int* __restrict__ partFill, const int* __restrict__ edgeBuf,
    const float4* __restrict__ in4, const float* __restrict__ gc, int gcOff,
    float4* __restrict__ out4, int nN, int doSoftmax)
{
    __shared__ float acc[4 * NP];
    spmm_part(blockIdx.x, threadIdx.x, acc, partFill, edgeBuf, in4, gc, gcOff,
              out4, nN, doSoftmax != 0);
}

extern "C" void kernel_launch(void* const* d_in, const int* in_sizes, int n_in,
                              void* d_out, int out_size, void* d_ws, size_t ws_size,
                              hipStream_t stream)
{
    const float4* x4  = (const float4*)d_in[0];
    const int* srcp   = (const int*)d_in[1];
    const int* dstp   = (const int*)d_in[2];
    const float* w1p  = (const float*)d_in[3];
    const float* Wd1p = (const float*)d_in[4];
    const float* b1p  = (const float*)d_in[5];
    const float* w2p  = (const float*)d_in[6];
    const float* Wd2p = (const float*)d_in[7];
    const float* b2p  = (const float*)d_in[8];
    const float* Woutp = (const float*)d_in[9];
    const float* boutp = (const float*)d_in[10];

    int nE = in_sizes[1];
    int nN = in_sizes[0] / D_FEAT;           // 50000

    // ws layout (floats): gc[8] pad->16 | u[4N] | v[4N] | partFill | edgeBuf
    float* ws = (float*)d_ws;
    float* gcp = ws;
    float* u   = ws + 16;
    float* v   = u + (size_t)nN * 4;
    int* partFill = (int*)(v + (size_t)nN * 4);
    int* edgeBuf  = partFill + 1024;
    float4* u4p = (float4*)u;
    float4* v4p = (float4*)v;
    float4* o4  = (float4*)d_out;

    void* args[] = { &x4, &srcp, &dstp, &w1p, &Wd1p, &b1p, &w2p, &Wd2p, &b2p,
                     &Woutp, &boutp, &partFill, &edgeBuf, &gcp, &u4p, &v4p,
                     &o4, &nN, &nE };
    hipError_t err = hipLaunchCooperativeKernel((const void*)mega_kernel,
                                                dim3(GRID), dim3(256),
                                                args, 0, stream);
    if (err != hipSuccess) {
        // fallback: identical math, 4 dispatches (r4 structure, known-good)
        hipMemsetAsync(partFill, 0, P_PARTS * sizeof(int), stream);
        xw_bucket_kernel<<<XW_BLOCKS + BK_BLOCKS, 256, 0, stream>>>(
            x4, srcp, dstp, w1p, Wd1p, b1p, w2p, Wd2p, b2p, Woutp, boutp,
            partFill, edgeBuf, gcp, u4p, nN, nE);
        spmm_kernel_sa<<<P_PARTS, 256, 0, stream>>>(partFill, edgeBuf, u4p,
                                                    gcp, 0, v4p, nN, 0);
        spmm_kernel_sa<<<P_PARTS, 256, 0, stream>>>(partFill, edgeBuf, v4p,
                                                    gcp, 4, o4, nN, 1);
    }
}

// Round 7
// 145.393 us; speedup vs baseline: 2.1784x; 2.1784x over previous
//
#include <hip/hip_runtime.h>
#include <hip/hip_bf16.h>

#define D_FEAT 128
#define NP 64                // nodes per partition
#define NP_SHIFT 6
#define P_PARTS 782          // ceil(50000/64)
#define CAP 1024             // edges per partition: mean 768, sd ~28 -> +9 sigma
#define EPB 3072             // edges per bucket block -> 196 bucket blocks
#define XW_BLOCKS 196        // ceil(50000/256)
#define BK_BLOCKS 196        // ceil(600000/3072)

// ---------------------------------------------------------------------------
// logits = A^2 (x @ W_all) + A(1 g^T) + 1 c^T ;  out = softmax(logits)
//   W_all = diag(w1) Wd1 diag(w2) Wd2 Wout  (128x4)
//   g = b1^T diag(w2) Wd2 Wout,  c = b2^T Wout + bout
// r6 lesson: cooperative grid.sync costs ~50us+ each on 8-XCD MI355X
// (device-scope L2 flush across non-coherent XCDs) -> mega-kernel 212us vs
// ~65us for plain dispatches. This is the r3 4-dispatch structure plus:
//   - spmm: wave-private LDS accumulators (no inter-wave ds_add contention)
//   - bucket: EPB=3072 (balanced with xw blocks; bigger contiguous scatter
//     chunks for edgeBuf writes)
// ---------------------------------------------------------------------------

__global__ __launch_bounds__(256) void fused_xw_bucket_kernel(
    const float4* __restrict__ x4,
    const int* __restrict__ src, const int* __restrict__ dst,
    const float* __restrict__ w1, const float* __restrict__ Wd1,
    const float* __restrict__ b1, const float* __restrict__ w2,
    const float* __restrict__ Wd2, const float* __restrict__ b2,
    const float* __restrict__ Wout, const float* __restrict__ bout,
    int* __restrict__ partFill, int* __restrict__ edgeBuf,
    float* __restrict__ gc, float4* __restrict__ u4, int nN, int nE)
{
    __shared__ int sm[2 * P_PARTS];          // bucket: hist+base; xw: T2+Wall
    int t = threadIdx.x, b = blockIdx.x;

    if (b < XW_BLOCKS) {
        // ---- weight fold (cheap, per block) ----
        float* T2   = (float*)sm;            // 64x4
        float* Wall = (float*)sm + 256;      // 128x4
        {
            int m = t >> 2, j = t & 3;
            float s = 0.f;
            for (int p = 0; p < 32; ++p) s += Wd2[m * 32 + p] * Wout[p * 4 + j];
            T2[t] = w2[m] * s;
        }
        __syncthreads();
        for (int idx = t; idx < 512; idx += 256) {
            int k = idx >> 2, j = idx & 3;
            float s = 0.f;
            for (int m = 0; m < 64; ++m) s += Wd1[k * 64 + m] * T2[m * 4 + j];
            Wall[idx] = w1[k] * s;
        }
        if (b == 0 && t < 4) {               // publish g, c
            float s = 0.f;
            for (int m = 0; m < 64; ++m) s += b1[m] * T2[m * 4 + t];
            gc[t] = s;
            float s2 = 0.f;
            for (int p = 0; p < 32; ++p) s2 += b2[p] * Wout[p * 4 + t];
            gc[4 + t] = s2 + bout[t];
        }
        __syncthreads();
        // ---- u = x @ W_all, thread-per-row ----
        int r = b * 256 + t;
        if (r < nN) {
            const float4* W = (const float4*)Wall;
            float4 acc = make_float4(0.f, 0.f, 0.f, 0.f);
            #pragma unroll 8
            for (int k4 = 0; k4 < 32; ++k4) {
                float4 xv = x4[(size_t)r * 32 + k4];
                float4 a0 = W[4 * k4 + 0];
                float4 a1 = W[4 * k4 + 1];
                float4 a2 = W[4 * k4 + 2];
                float4 a3 = W[4 * k4 + 3];
                acc.x += xv.x * a0.x + xv.y * a1.x + xv.z * a2.x + xv.w * a3.x;
                acc.y += xv.x * a0.y + xv.y * a1.y + xv.z * a2.y + xv.w * a3.y;
                acc.z += xv.x * a0.z + xv.y * a1.z + xv.z * a2.z + xv.w * a3.z;
                acc.w += xv.x * a0.w + xv.y * a1.w + xv.z * a2.w + xv.w * a3.w;
            }
            u4[r] = acc;
        }
    } else {
        // ---- bucket EPB edges by dst partition, edges reg-cached ----
        int bb = b - XW_BLOCKS;
        int* hist = sm;
        int* base = sm + P_PARTS;
        for (int p = t; p < P_PARTS; p += 256) hist[p] = 0;
        __syncthreads();
        const int4* dst4 = (const int4*)dst;
        const int4* src4 = (const int4*)src;
        int nE4  = nE >> 2;
        int b4   = bb * (EPB / 4);
        int end4 = min(b4 + EPB / 4, nE4);
        int4 da[3], sa[3];
        bool va[3];
        #pragma unroll
        for (int it = 0; it < 3; ++it) {
            int i = b4 + it * 256 + t;
            va[it] = i < end4;
            if (va[it]) { da[it] = dst4[i]; sa[it] = src4[i]; }
        }
        #pragma unroll
        for (int it = 0; it < 3; ++it) {
            if (va[it]) {
                atomicAdd(&hist[da[it].x >> NP_SHIFT], 1);
                atomicAdd(&hist[da[it].y >> NP_SHIFT], 1);
                atomicAdd(&hist[da[it].z >> NP_SHIFT], 1);
                atomicAdd(&hist[da[it].w >> NP_SHIFT], 1);
            }
        }
        __syncthreads();
        for (int p = t; p < P_PARTS; p += 256) {
            int h = hist[p];
            base[p] = h ? atomicAdd(&partFill[p], h) : 0;
        }
        __syncthreads();
        auto place = [&](int d, int s) {
            int p = d >> NP_SHIFT;
            int rank = atomicSub(&hist[p], 1) - 1;
            int pos = base[p] + rank;
            if (pos < CAP)
                edgeBuf[p * CAP + pos] = s | ((d & (NP - 1)) << 16);
        };
        #pragma unroll
        for (int it = 0; it < 3; ++it) {
            if (va[it]) {
                place(da[it].x, sa[it].x);
                place(da[it].y, sa[it].y);
                place(da[it].z, sa[it].z);
                place(da[it].w, sa[it].w);
            }
        }
    }
}

// One block per 64-node partition. Wave-private LDS accumulators (4 copies)
// remove inter-wave ds_add serialization; 4 independent gathers per thread.
__global__ __launch_bounds__(256) void spmm_kernel(
    const int* __restrict__ partFill, const int* __restrict__ edgeBuf,
    const float4* __restrict__ in4, const float* __restrict__ gc, int gcOff,
    float4* __restrict__ out4, int nN, int doSoftmax)
{
    __shared__ float acc[4 * 4 * NP];        // [wave][c][dl] = 4KB
    int t = threadIdx.x, p = blockIdx.x;
    acc[t] = 0.f; acc[t + 256] = 0.f; acc[t + 512] = 0.f; acc[t + 768] = 0.f;
    __syncthreads();
    float* my = acc + (t >> 6) * (4 * NP);   // this wave's copy
    int n = min(partFill[p], CAP);
    const int4* eb4 = (const int4*)(edgeBuf + p * CAP);
    int i0 = t * 4;
    if (i0 < n) {
        int4 e4 = eb4[t];
        int ne = n - i0;                     // >= 1
        float4 v0 = in4[e4.x & 0xFFFF];
        float4 v1 = (ne > 1) ? in4[e4.y & 0xFFFF] : make_float4(0, 0, 0, 0);
        float4 v2 = (ne > 2) ? in4[e4.z & 0xFFFF] : make_float4(0, 0, 0, 0);
        float4 v3 = (ne > 3) ? in4[e4.w & 0xFFFF] : make_float4(0, 0, 0, 0);
        int d0 = e4.x >> 16, d1 = e4.y >> 16, d2 = e4.z >> 16, d3 = e4.w >> 16;
        atomicAdd(&my[0 * NP + d0], v0.x);
        atomicAdd(&my[1 * NP + d0], v0.y);
        atomicAdd(&my[2 * NP + d0], v0.z);
        atomicAdd(&my[3 * NP + d0], v0.w);
        if (ne > 1) {
            atomicAdd(&my[0 * NP + d1], v1.x);
            atomicAdd(&my[1 * NP + d1], v1.y);
            atomicAdd(&my[2 * NP + d1], v1.z);
            atomicAdd(&my[3 * NP + d1], v1.w);
        }
        if (ne > 2) {
            atomicAdd(&my[0 * NP + d2], v2.x);
            atomicAdd(&my[1 * NP + d2], v2.y);
            atomicAdd(&my[2 * NP + d2], v2.z);
            atomicAdd(&my[3 * NP + d2], v2.w);
        }
        if (ne > 3) {
            atomicAdd(&my[0 * NP + d3], v3.x);
            atomicAdd(&my[1 * NP + d3], v3.y);
            atomicAdd(&my[2 * NP + d3], v3.z);
            atomicAdd(&my[3 * NP + d3], v3.w);
        }
    }
    __syncthreads();
    if (t < NP) {
        int node = p * NP + t;
        if (node < nN) {
            float lx = acc[0 * NP + t] + acc[256 + 0 * NP + t]
                     + acc[512 + 0 * NP + t] + acc[768 + 0 * NP + t] + gc[gcOff + 0];
            float ly = acc[1 * NP + t] + acc[256 + 1 * NP + t]
                     + acc[512 + 1 * NP + t] + acc[768 + 1 * NP + t] + gc[gcOff + 1];
            float lz = acc[2 * NP + t] + acc[256 + 2 * NP + t]
                     + acc[512 + 2 * NP + t] + acc[768 + 2 * NP + t] + gc[gcOff + 2];
            float lw = acc[3 * NP + t] + acc[256 + 3 * NP + t]
                     + acc[512 + 3 * NP + t] + acc[768 + 3 * NP + t] + gc[gcOff + 3];
            if (doSoftmax) {
                float m = fmaxf(fmaxf(lx, ly), fmaxf(lz, lw));
                float ex = __expf(lx - m);
                float ey = __expf(ly - m);
                float ez = __expf(lz - m);
                float ew = __expf(lw - m);
                float r = 1.f / (ex + ey + ez + ew);
                out4[node] = make_float4(ex * r, ey * r, ez * r, ew * r);
            } else {
                out4[node] = make_float4(lx, ly, lz, lw);
            }
        }
    }
}

extern "C" void kernel_launch(void* const* d_in, const int* in_sizes, int n_in,
                              void* d_out, int out_size, void* d_ws, size_t ws_size,
                              hipStream_t stream)
{
    const float4* x4  = (const float4*)d_in[0];
    const int* srcp   = (const int*)d_in[1];
    const int* dstp   = (const int*)d_in[2];
    const float* w1p  = (const float*)d_in[3];
    const float* Wd1p = (const float*)d_in[4];
    const float* b1p  = (const float*)d_in[5];
    const float* w2p  = (const float*)d_in[6];
    const float* Wd2p = (const float*)d_in[7];
    const float* b2p  = (const float*)d_in[8];
    const float* Woutp = (const float*)d_in[9];
    const float* boutp = (const float*)d_in[10];

    int nE = in_sizes[1];
    int nN = in_sizes[0] / D_FEAT;           // 50000

    // ws layout (floats): gc[8] pad->16 | u[4N] | v[4N] | partFill | edgeBuf
    float* ws = (float*)d_ws;
    float* gcp = ws;
    float* u   = ws + 16;                    // 64B aligned
    float* v   = u + (size_t)nN * 4;
    int* partFill = (int*)(v + (size_t)nN * 4);
    int* edgeBuf  = partFill + 1024;
    float4* u4p = (float4*)u;
    float4* v4p = (float4*)v;
    float4* o4  = (float4*)d_out;

    hipMemsetAsync(partFill, 0, P_PARTS * sizeof(int), stream);
    fused_xw_bucket_kernel<<<XW_BLOCKS + BK_BLOCKS, 256, 0, stream>>>(
        x4, srcp, dstp, w1p, Wd1p, b1p, w2p, Wd2p, b2p, Woutp, boutp,
        partFill, edgeBuf, gcp, u4p, nN, nE);
    spmm_kernel<<<P_PARTS, 256, 0, stream>>>(partFill, edgeBuf, u4p,
                                             gcp, 0, v4p, nN, 0);
    spmm_kernel<<<P_PARTS, 256, 0, stream>>>(partFill, edgeBuf, v4p,
                                             gcp, 4, o4, nN, 1);
}